// Round 9
// baseline (136.607 us; speedup 1.0000x reference)
//
#include <hip/hip_runtime.h>
#include <math.h>

#define NSAMP 131072

typedef _Float16 half8v __attribute__((ext_vector_type(8)));
typedef __fp16   fp16x2 __attribute__((ext_vector_type(2)));
typedef __fp16   fp16x4 __attribute__((ext_vector_type(4)));
typedef __fp16   fp16x8 __attribute__((ext_vector_type(8)));
typedef float    f32x4  __attribute__((ext_vector_type(4)));
typedef float    f32x8  __attribute__((ext_vector_type(8)));

__device__ __forceinline__ float fast_tanh(float x) {
    // valid for all x: exp2 saturates to 0/inf, rcp gives exact +-1 limits
    float e = __builtin_amdgcn_exp2f(x * 2.885390081777927f); // exp(2x)
    return fmaf(-2.0f, __builtin_amdgcn_rcpf(e + 1.0f), 1.0f);
}

__device__ __forceinline__ half8v pack8rtz(f32x8 v) {
    fp16x2 p0 = __builtin_amdgcn_cvt_pkrtz(v[0], v[1]);
    fp16x2 p1 = __builtin_amdgcn_cvt_pkrtz(v[2], v[3]);
    fp16x2 p2 = __builtin_amdgcn_cvt_pkrtz(v[4], v[5]);
    fp16x2 p3 = __builtin_amdgcn_cvt_pkrtz(v[6], v[7]);
    fp16x4 q0 = __builtin_shufflevector(p0, p1, 0, 1, 2, 3);
    fp16x4 q1 = __builtin_shufflevector(p2, p3, 0, 1, 2, 3);
    fp16x8 r  = __builtin_shufflevector(q0, q1, 0, 1, 2, 3, 4, 5, 6, 7);
    return __builtin_bit_cast(half8v, r);
}

__global__ __launch_bounds__(256, 1)
void cnf_logp_kernel(const float* __restrict__ xin, const float* __restrict__ tin,
                     const float* __restrict__ W1, const float* __restrict__ b1,
                     const float* __restrict__ W2, const float* __restrict__ b2,
                     const float* __restrict__ W3, const float* __restrict__ b3,
                     const float* __restrict__ vol, float* __restrict__ out)
{
    const int tid  = threadIdx.x;
    const int lane = tid & 63;
    const int col  = lane & 15;   // sample slot (B/C column); A-row for weight frags
    const int g    = lane >> 4;   // lane group

    // slot k-map shared by ALL frags (hw-map mismatches cancel):
    //   k(e,g) = 4g + (e&3) + 16*(e>>2); e>=4 -> slot >= 16

    // ---------------- layer-1 MFMA A-frags (static) ----------------
    half8v A1[4];   // [kq], rows = k within quarter (= col)
    #pragma unroll
    for (int kq = 0; kq < 4; ++kq) {
        half8v a;
        #pragma unroll
        for (int e = 0; e < 8; ++e) a[e] = (_Float16)0.0f;
        const int krow = kq*16 + col;
        #pragma unroll
        for (int e = 0; e < 4; ++e) {
            const float w = W1[e*64 + krow];
            const _Float16 whi = (_Float16)w;
            const _Float16 wlo = (_Float16)(w - (float)whi);
            _Float16 v = (_Float16)0.0f;
            if (g == 0 || g == 2)      v = whi;
            else if (g == 1)           v = wlo;
            else {                     // g == 3: bias slots 12/13
                const float bv = b1[krow];
                const _Float16 bhi = (_Float16)bv;
                if (e == 0)      v = bhi;
                else if (e == 1) v = (_Float16)(bv - (float)bhi);
            }
            a[e] = v;
        }
        A1[kq] = a;
    }

    // ---------------- layer-2 weight A-frags (rows = j) ----------------
    half8v AW2[8];   // [nt*2+kh] : A[j = nt*16+col, k] = W2[k, j]
    half8v AHW[8];   // H[k,j] = W2[k,j] * sum_i W1[i,k] W3[j,i]
    #pragma unroll
    for (int nt = 0; nt < 4; ++nt) {
        const int j = nt*16 + col;
        const float w3j0 = W3[j*3+0], w3j1 = W3[j*3+1], w3j2 = W3[j*3+2];
        #pragma unroll
        for (int kh = 0; kh < 2; ++kh) {
            #pragma unroll
            for (int e = 0; e < 8; ++e) {
                const int k = kh*32 + 4*g + (e & 3) + 16*(e >> 2);
                const float w2v = W2[k*64 + j];
                const float gv  = W1[0*64+k]*w3j0 + W1[1*64+k]*w3j1 + W1[2*64+k]*w3j2;
                AW2[nt*2 + kh][e] = (_Float16)w2v;
                AHW[nt*2 + kh][e] = (_Float16)(w2v * gv);
            }
        }
    }
    // b2 in OUTPUT-j indexing: j_out = nt*16 + 4g + r
    f32x4 b2v[4];
    #pragma unroll
    for (int nt = 0; nt < 4; ++nt) {
        #pragma unroll
        for (int r = 0; r < 4; ++r) b2v[nt][r] = b2[nt*16 + 4*g + r];
    }
    // W3 A-frags for the f-MFMA: rows = channel (col<3), K = j
    half8v A3[2];
    #pragma unroll
    for (int kp = 0; kp < 2; ++kp) {
        #pragma unroll
        for (int e = 0; e < 8; ++e) {
            const int j = kp*32 + 4*g + (e & 3) + 16*(e >> 2);
            A3[kp][e] = (col < 3) ? (_Float16)W3[j*3 + col] : (_Float16)0.0f;
        }
    }
    const float b3c0 = b3[0], b3c1 = b3[1], b3c2 = b3[2];

    // ---------------- two sample streams per wave ----------------
    const int idxA = blockIdx.x*128 + (tid >> 6)*16 + col;
    const int idxB = idxA + 64;

    float x0v[2], x1v[2], x2v[2], t0[2];
    x0v[0] = xin[idxA*3 + 0]; x1v[0] = xin[idxA*3 + 1]; x2v[0] = xin[idxA*3 + 2];
    x0v[1] = xin[idxB*3 + 0]; x1v[1] = xin[idxB*3 + 1]; x2v[1] = xin[idxB*3 + 2];
    t0[0] = tin[idxA]; t0[1] = tin[idxB];

    float z0[2], z1[2], z2[2], dacc[2];
    float kz0[2], kz1[2], kz2[2], sa0[2], sa1[2], sa2[2];
    #pragma unroll
    for (int ss = 0; ss < 2; ++ss) {
        z0[ss] = x0v[ss]; z1[ss] = x1v[ss]; z2[ss] = x2v[ss];
        dacc[ss] = 0.f; kz0[ss] = 0.f; kz1[ss] = 0.f; kz2[ss] = 0.f;
        sa0[ss] = 0.f; sa1[ss] = 0.f; sa2[ss] = 0.f;
    }
    const float hstep = 0.25f;
    const bool g2f = (g == 2), g3f = (g == 3);

    #pragma unroll 1
    for (int it = 0; it < 16; ++it) {
        const int st   = it & 3;
        const int step = it >> 2;
        const float alpha = (st == 0) ? 0.0f : ((st == 3) ? hstep : 0.5f * hstep);
        const float wgt   = (st == 1 || st == 2) ? (hstep * (1.0f/3.0f)) : (hstep * (1.0f/6.0f));
        const float s     = (float)step * hstep + alpha;
        const float oms   = 1.0f - s;

        // ---- layer 1 via MFMA (both streams) ----
        half8v B1[2];
        #pragma unroll
        for (int ss = 0; ss < 2; ++ss) {
            const float zi0 = fmaf(alpha, kz0[ss], z0[ss]);
            const float zi1 = fmaf(alpha, kz1[ss], z1[ss]);
            const float zi2 = fmaf(alpha, kz2[ss], z2[ss]);
            const float tt  = t0[ss] * oms;
            const _Float16 z0h = (_Float16)zi0, z1h = (_Float16)zi1,
                           z2h = (_Float16)zi2, tth = (_Float16)tt;
            const _Float16 z0l = (_Float16)(zi0 - (float)z0h);
            const _Float16 z1l = (_Float16)(zi1 - (float)z1h);
            const _Float16 z2l = (_Float16)(zi2 - (float)z2h);
            const _Float16 ttl = (_Float16)(tt  - (float)tth);
            half8v B;
            #pragma unroll
            for (int e = 0; e < 8; ++e) B[e] = (_Float16)0.0f;
            B[0] = g3f ? (_Float16)1.0f : (g2f ? z0l : z0h);
            B[1] = g3f ? (_Float16)1.0f : (g2f ? z1l : z1h);
            B[2] = g3f ? (_Float16)0.0f : (g2f ? z2l : z2h);
            B[3] = g3f ? (_Float16)0.0f : (g2f ? ttl : tth);
            B1[ss] = B;
        }

        f32x8 hv[2][2];   // [ss][half], element kq*4+r (mod 8)
        #pragma unroll
        for (int ss = 0; ss < 2; ++ss) {
            #pragma unroll
            for (int kq = 0; kq < 4; ++kq) {
                f32x4 z4; z4[0]=0.f; z4[1]=0.f; z4[2]=0.f; z4[3]=0.f;
                z4 = __builtin_amdgcn_mfma_f32_16x16x32_f16(A1[kq], B1[ss], z4, 0, 0, 0);
                #pragma unroll
                for (int r = 0; r < 4; ++r)
                    hv[ss][kq >> 1][(kq & 1)*4 + r] = fast_tanh(z4[r]);
            }
        }

        // ---- pack h -> layer-2 B-frags ----
        half8v BH[2][2], BQ[2][2];
        half8v hone;
        #pragma unroll
        for (int e = 0; e < 8; ++e) hone[e] = (_Float16)1.0f;
        #pragma unroll
        for (int ss = 0; ss < 2; ++ss) {
            #pragma unroll
            for (int kh = 0; kh < 2; ++kh) {
                BH[ss][kh] = pack8rtz(hv[ss][kh]);
                BQ[ss][kh] = hone - BH[ss][kh]*BH[ss][kh];   // s1 = 1 - h^2
            }
        }

        // ---- layer 2 + divergence bilinear (cs folded): D[j, sample] ----
        f32x4 a2[2][4], d2[2][4];
        #pragma unroll
        for (int ss = 0; ss < 2; ++ss) {
            #pragma unroll
            for (int nt = 0; nt < 4; ++nt) {
                f32x4 acc = b2v[nt];
                acc = __builtin_amdgcn_mfma_f32_16x16x32_f16(AW2[nt*2+0], BH[ss][0], acc, 0, 0, 0);
                acc = __builtin_amdgcn_mfma_f32_16x16x32_f16(AW2[nt*2+1], BH[ss][1], acc, 0, 0, 0);
                a2[ss][nt] = acc;
                f32x4 z4; z4[0]=0.f; z4[1]=0.f; z4[2]=0.f; z4[3]=0.f;
                z4  = __builtin_amdgcn_mfma_f32_16x16x32_f16(AHW[nt*2+0], BQ[ss][0], z4, 0, 0, 0);
                z4  = __builtin_amdgcn_mfma_f32_16x16x32_f16(AHW[nt*2+1], BQ[ss][1], z4, 0, 0, 0);
                d2[ss][nt] = z4;
            }
        }

        // ---- epilogue: per-lane j-slice (j = nt*16 + 4g + r), sample = col ----
        float pdv[2];
        f32x8 h2v[2][2];
        #pragma unroll
        for (int ss = 0; ss < 2; ++ss) {
            pdv[ss] = 0.0f;
            #pragma unroll
            for (int nt = 0; nt < 4; ++nt) {
                #pragma unroll
                for (int r = 0; r < 4; ++r) {
                    const float h2 = fast_tanh(a2[ss][nt][r]);
                    h2v[ss][nt >> 1][(nt & 1)*4 + r] = h2;
                    const float s2 = fmaf(-h2, h2, 1.0f);
                    pdv[ss] = fmaf(s2, d2[ss][nt][r], pdv[ss]);
                }
            }
        }
        // f = h2 @ W3 via 2nd-level MFMA
        f32x4 fD[2];
        #pragma unroll
        for (int ss = 0; ss < 2; ++ss) {
            half8v B2h0 = pack8rtz(h2v[ss][0]);
            half8v B2h1 = pack8rtz(h2v[ss][1]);
            f32x4 f4; f4[0]=0.f; f4[1]=0.f; f4[2]=0.f; f4[3]=0.f;
            f4 = __builtin_amdgcn_mfma_f32_16x16x32_f16(A3[0], B2h0, f4, 0, 0, 0);
            f4 = __builtin_amdgcn_mfma_f32_16x16x32_f16(A3[1], B2h1, f4, 0, 0, 0);
            fD[ss] = f4;
        }

        // ---- reductions + RK4 stage update (per stream) ----
        #pragma unroll
        for (int ss = 0; ss < 2; ++ss) {
            float pd = pdv[ss];
            pd += __shfl_xor(pd, 16);
            pd += __shfl_xor(pd, 32);
            const float f0 = __shfl(fD[ss][0], col) + b3c0;
            const float f1 = __shfl(fD[ss][1], col) + b3c1;
            const float f2 = __shfl(fD[ss][2], col) + b3c2;

            const float v0 = -t0[ss] * f0, v1 = -t0[ss] * f1, v2 = -t0[ss] * f2;
            const float vd =  t0[ss] * pd;
            kz0[ss] = v0; kz1[ss] = v1; kz2[ss] = v2;
            dacc[ss] = fmaf(wgt, vd, dacc[ss]);
            if (st == 0) { sa0[ss] = wgt*v0; sa1[ss] = wgt*v1; sa2[ss] = wgt*v2; }
            else {
                sa0[ss] = fmaf(wgt, v0, sa0[ss]);
                sa1[ss] = fmaf(wgt, v1, sa1[ss]);
                sa2[ss] = fmaf(wgt, v2, sa2[ss]);
            }
            if (st == 3) { z0[ss] += sa0[ss]; z1[ss] += sa1[ss]; z2[ss] += sa2[ss]; }
        }
    }

    // ---------------- mask, grid-sample, store (group 0 only) ----------------
    if (g == 0) {
        #pragma unroll
        for (int ss = 0; ss < 2; ++ss) {
            const bool m = (t0[ss] > 0.0f);
            const float q0 = m ? z0[ss] : x0v[ss];
            const float q1 = m ? z1[ss] : x1v[ss];
            const float q2 = m ? z2[ss] : x2v[ss];
            const float dfin = m ? dacc[ss] : 0.0f;

            const float px = ((q0 * 0.2f + 1.0f) * 100.0f - 1.0f) * 0.5f;
            const float py = ((q1 * 0.2f + 1.0f) * 100.0f - 1.0f) * 0.5f;
            const float pz = ((q2 * 0.2f + 1.0f) * 100.0f - 1.0f) * 0.5f;
            const float fx = floorf(px), fy = floorf(py), fz = floorf(pz);
            const int ix0 = (int)fx, iy0 = (int)fy, iz0 = (int)fz;
            const float wx1 = px - fx, wy1 = py - fy, wz1 = pz - fz;

            float gs = 0.0f;
            #pragma unroll
            for (int c = 0; c < 8; ++c) {
                const int dxc = c & 1, dyc = (c >> 1) & 1, dzc = (c >> 2) & 1;
                const int ix = ix0 + dxc, iy = iy0 + dyc, iz = iz0 + dzc;
                const float w = (dxc ? wx1 : 1.0f - wx1)
                              * (dyc ? wy1 : 1.0f - wy1)
                              * (dzc ? wz1 : 1.0f - wz1);
                if (ix >= 0 && ix < 100 && iy >= 0 && iy < 100 && iz >= 0 && iz < 100)
                    gs += vol[(iz * 100 + iy) * 100 + ix] * w;
            }
            out[ss ? idxB : idxA] = gs - dfin;
        }
    }
}

extern "C" void kernel_launch(void* const* d_in, const int* in_sizes, int n_in,
                              void* d_out, int out_size, void* d_ws, size_t ws_size,
                              hipStream_t stream) {
    const float* x    = (const float*)d_in[0];
    const float* t    = (const float*)d_in[1];
    const float* W1   = (const float*)d_in[2];
    const float* b1   = (const float*)d_in[3];
    const float* W2   = (const float*)d_in[4];
    const float* b2   = (const float*)d_in[5];
    const float* W3   = (const float*)d_in[6];
    const float* b3   = (const float*)d_in[7];
    const float* vol  = (const float*)d_in[8];
    float* out = (float*)d_out;

    dim3 grid(NSAMP / 128), block(256);   // 4 waves/block, 32 samples/wave (2 streams)
    cnf_logp_kernel<<<grid, block, 0, stream>>>(x, t, W1, b1, W2, b2, W3, b3, vol, out);
}

// Round 10
// 123.782 us; speedup vs baseline: 1.1036x; 1.1036x over previous
//
#include <hip/hip_runtime.h>
#include <math.h>

#define NSAMP 131072

typedef _Float16 half8v __attribute__((ext_vector_type(8)));
typedef __fp16   fp16x2 __attribute__((ext_vector_type(2)));
typedef __fp16   fp16x4 __attribute__((ext_vector_type(4)));
typedef __fp16   fp16x8 __attribute__((ext_vector_type(8)));
typedef float    f32x4  __attribute__((ext_vector_type(4)));
typedef float    f32x8  __attribute__((ext_vector_type(8)));

// Pade-CF [5/4]: tanh(x) ~= x(945+105t+t^2)/(945+420t+15t^2), t=x^2.
// ratio >= 1 for |x| >= 3.97 (monotone ~x/15 asymptote) -> med3 clamp covers tails.
// max interior error ~1.8e-3 at |x|~3.4. 8 VALU + 1 trans (vs 3 VALU + 2 trans).
__device__ __forceinline__ float pade_tanh(float x) {
    const float t = x * x;
    const float n = fmaf(t, t + 105.0f, 945.0f);          // 945 + 105t + t^2
    const float d = fmaf(t, fmaf(t, 15.0f, 420.0f), 945.0f); // 945 + 420t + 15t^2
    const float r = (x * n) * __builtin_amdgcn_rcpf(d);
    return fminf(fmaxf(r, -1.0f), 1.0f);                  // v_med3_f32
}

__device__ __forceinline__ half8v pack8rtz(f32x8 v) {
    fp16x2 p0 = __builtin_amdgcn_cvt_pkrtz(v[0], v[1]);
    fp16x2 p1 = __builtin_amdgcn_cvt_pkrtz(v[2], v[3]);
    fp16x2 p2 = __builtin_amdgcn_cvt_pkrtz(v[4], v[5]);
    fp16x2 p3 = __builtin_amdgcn_cvt_pkrtz(v[6], v[7]);
    fp16x4 q0 = __builtin_shufflevector(p0, p1, 0, 1, 2, 3);
    fp16x4 q1 = __builtin_shufflevector(p2, p3, 0, 1, 2, 3);
    fp16x8 r  = __builtin_shufflevector(q0, q1, 0, 1, 2, 3, 4, 5, 6, 7);
    return __builtin_bit_cast(half8v, r);
}

__global__ __launch_bounds__(256, 2)
void cnf_logp_kernel(const float* __restrict__ xin, const float* __restrict__ tin,
                     const float* __restrict__ W1, const float* __restrict__ b1,
                     const float* __restrict__ W2, const float* __restrict__ b2,
                     const float* __restrict__ W3, const float* __restrict__ b3,
                     const float* __restrict__ vol, float* __restrict__ out)
{
    const int tid  = threadIdx.x;
    const int lane = tid & 63;
    const int col  = lane & 15;   // sample slot (B/C column); A-row for weight frags
    const int g    = lane >> 4;   // lane group

    // slot k-map shared by ALL frags (hw-map mismatches cancel):
    //   k(e,g) = 4g + (e&3) + 16*(e>>2); e>=4 -> slot >= 16

    // ---------------- layer-1 MFMA A-frags (static) ----------------
    half8v A1[4];   // [kq], rows = k within quarter (= col)
    #pragma unroll
    for (int kq = 0; kq < 4; ++kq) {
        half8v a;
        #pragma unroll
        for (int e = 0; e < 8; ++e) a[e] = (_Float16)0.0f;
        const int krow = kq*16 + col;
        #pragma unroll
        for (int e = 0; e < 4; ++e) {
            const float w = W1[e*64 + krow];
            const _Float16 whi = (_Float16)w;
            const _Float16 wlo = (_Float16)(w - (float)whi);
            _Float16 v = (_Float16)0.0f;
            if (g == 0 || g == 2)      v = whi;
            else if (g == 1)           v = wlo;
            else {                     // g == 3: bias slots 12/13
                const float bv = b1[krow];
                const _Float16 bhi = (_Float16)bv;
                if (e == 0)      v = bhi;
                else if (e == 1) v = (_Float16)(bv - (float)bhi);
            }
            a[e] = v;
        }
        A1[kq] = a;
    }

    // ---------------- layer-2 weight A-frags (rows = j) ----------------
    half8v AW2[8];   // [nt*2+kh] : A[j = nt*16+col, k] = W2[k, j]
    half8v AHW[8];   // H[k,j] = W2[k,j] * sum_i W1[i,k] W3[j,i]
    #pragma unroll
    for (int nt = 0; nt < 4; ++nt) {
        const int j = nt*16 + col;
        const float w3j0 = W3[j*3+0], w3j1 = W3[j*3+1], w3j2 = W3[j*3+2];
        #pragma unroll
        for (int kh = 0; kh < 2; ++kh) {
            #pragma unroll
            for (int e = 0; e < 8; ++e) {
                const int k = kh*32 + 4*g + (e & 3) + 16*(e >> 2);
                const float w2v = W2[k*64 + j];
                const float gv  = W1[0*64+k]*w3j0 + W1[1*64+k]*w3j1 + W1[2*64+k]*w3j2;
                AW2[nt*2 + kh][e] = (_Float16)w2v;
                AHW[nt*2 + kh][e] = (_Float16)(w2v * gv);
            }
        }
    }
    // b2 in OUTPUT-j indexing: j_out = nt*16 + 4g + r
    f32x4 b2v[4];
    #pragma unroll
    for (int nt = 0; nt < 4; ++nt) {
        #pragma unroll
        for (int r = 0; r < 4; ++r) b2v[nt][r] = b2[nt*16 + 4*g + r];
    }
    // W3 A-frags for the f-MFMA: rows = channel (col<3), K = j
    half8v A3[2];
    #pragma unroll
    for (int kp = 0; kp < 2; ++kp) {
        #pragma unroll
        for (int e = 0; e < 8; ++e) {
            const int j = kp*32 + 4*g + (e & 3) + 16*(e >> 2);
            A3[kp][e] = (col < 3) ? (_Float16)W3[j*3 + col] : (_Float16)0.0f;
        }
    }
    const float b3c0 = b3[0], b3c1 = b3[1], b3c2 = b3[2];

    // ---------------- per-sample state (sample = col, replicated x4 groups) ----------------
    const int idx = blockIdx.x*64 + (tid >> 6)*16 + col;
    const float x0v = xin[idx*3 + 0], x1v = xin[idx*3 + 1], x2v = xin[idx*3 + 2];
    const float t0  = tin[idx];

    float z0 = x0v, z1 = x1v, z2 = x2v;
    float dacc = 0.0f;
    const float hstep = 0.25f;
    float kz0 = 0.f, kz1 = 0.f, kz2 = 0.f;
    float sa0 = 0.f, sa1 = 0.f, sa2 = 0.f;

    const bool g2f = (g == 2), g3f = (g == 3);

    #pragma unroll 1
    for (int it = 0; it < 16; ++it) {
        const int st   = it & 3;
        const int step = it >> 2;
        const float alpha = (st == 0) ? 0.0f : ((st == 3) ? hstep : 0.5f * hstep);
        const float wgt   = (st == 1 || st == 2) ? (hstep * (1.0f/3.0f)) : (hstep * (1.0f/6.0f));
        const float s     = (float)step * hstep + alpha;
        const float zi0 = fmaf(alpha, kz0, z0);
        const float zi1 = fmaf(alpha, kz1, z1);
        const float zi2 = fmaf(alpha, kz2, z2);
        const float tt  = t0 * (1.0f - s);

        // ---- layer 1 via MFMA: B-frag carries [zhi | zhi | zlo | 1] by group ----
        const _Float16 z0h = (_Float16)zi0, z1h = (_Float16)zi1,
                       z2h = (_Float16)zi2, tth = (_Float16)tt;
        const _Float16 z0l = (_Float16)(zi0 - (float)z0h);
        const _Float16 z1l = (_Float16)(zi1 - (float)z1h);
        const _Float16 z2l = (_Float16)(zi2 - (float)z2h);
        const _Float16 ttl = (_Float16)(tt  - (float)tth);
        half8v B1;
        #pragma unroll
        for (int e = 0; e < 8; ++e) B1[e] = (_Float16)0.0f;
        B1[0] = g3f ? (_Float16)1.0f : (g2f ? z0l : z0h);
        B1[1] = g3f ? (_Float16)1.0f : (g2f ? z1l : z1h);
        B1[2] = g3f ? (_Float16)0.0f : (g2f ? z2l : z2h);
        B1[3] = g3f ? (_Float16)0.0f : (g2f ? ttl : tth);

        f32x8 hv[2];   // [kh], element (kq&1)*4 + r
        #pragma unroll
        for (int kq = 0; kq < 4; ++kq) {
            f32x4 z4; z4[0]=0.f; z4[1]=0.f; z4[2]=0.f; z4[3]=0.f;
            z4 = __builtin_amdgcn_mfma_f32_16x16x32_f16(A1[kq], B1, z4, 0, 0, 0);
            #pragma unroll
            for (int r = 0; r < 4; ++r)
                hv[kq >> 1][(kq & 1)*4 + r] = pade_tanh(z4[r]);
        }

        // ---- pack h -> layer-2 B-frags ----
        half8v BH[2], BQ[2];
        half8v hone;
        #pragma unroll
        for (int e = 0; e < 8; ++e) hone[e] = (_Float16)1.0f;
        #pragma unroll
        for (int kh = 0; kh < 2; ++kh) {
            BH[kh] = pack8rtz(hv[kh]);
            BQ[kh] = hone - BH[kh]*BH[kh];   // s1 = 1 - h^2 (packed)
        }

        // ---- layer 2 + divergence bilinear (cs folded): D[j, sample] ----
        f32x4 a2[4], d2[4];
        #pragma unroll
        for (int nt = 0; nt < 4; ++nt) {
            f32x4 acc = b2v[nt];
            acc = __builtin_amdgcn_mfma_f32_16x16x32_f16(AW2[nt*2+0], BH[0], acc, 0, 0, 0);
            acc = __builtin_amdgcn_mfma_f32_16x16x32_f16(AW2[nt*2+1], BH[1], acc, 0, 0, 0);
            a2[nt] = acc;
            f32x4 z4; z4[0]=0.f; z4[1]=0.f; z4[2]=0.f; z4[3]=0.f;
            z4  = __builtin_amdgcn_mfma_f32_16x16x32_f16(AHW[nt*2+0], BQ[0], z4, 0, 0, 0);
            z4  = __builtin_amdgcn_mfma_f32_16x16x32_f16(AHW[nt*2+1], BQ[1], z4, 0, 0, 0);
            d2[nt] = z4;
        }

        // ---- epilogue: per-lane j-slice (j = nt*16 + 4g + r), sample = col ----
        f32x8 h2v[2];  // [nt>>1], element (nt&1)*4 + r
        float pdv = 0.0f;
        #pragma unroll
        for (int nt = 0; nt < 4; ++nt) {
            #pragma unroll
            for (int r = 0; r < 4; ++r) {
                const float h2 = pade_tanh(a2[nt][r]);
                h2v[nt >> 1][(nt & 1)*4 + r] = h2;
                const float s2 = fmaf(-h2, h2, 1.0f);
                pdv = fmaf(s2, d2[nt][r], pdv);
            }
        }
        // f = h2 @ W3 via 2nd-level MFMA: tanh(a2) repacks as K=j B-frag
        half8v B2h0 = pack8rtz(h2v[0]);
        half8v B2h1 = pack8rtz(h2v[1]);
        f32x4 fD; fD[0]=0.f; fD[1]=0.f; fD[2]=0.f; fD[3]=0.f;
        fD = __builtin_amdgcn_mfma_f32_16x16x32_f16(A3[0], B2h0, fD, 0, 0, 0);
        fD = __builtin_amdgcn_mfma_f32_16x16x32_f16(A3[1], B2h1, fD, 0, 0, 0);

        // dv: sum over 4 groups; f: rows 0..2 live in group-0 lanes
        pdv += __shfl_xor(pdv, 16);
        pdv += __shfl_xor(pdv, 32);
        const float f0 = __shfl(fD[0], col) + b3c0;
        const float f1 = __shfl(fD[1], col) + b3c1;
        const float f2 = __shfl(fD[2], col) + b3c2;

        // ---- RK4 stage update (sample = col, replicated across groups) ----
        const float v0 = -t0 * f0, v1 = -t0 * f1, v2 = -t0 * f2;
        const float vd =  t0 * pdv;
        kz0 = v0; kz1 = v1; kz2 = v2;
        dacc = fmaf(wgt, vd, dacc);
        if (st == 0) { sa0 = wgt*v0; sa1 = wgt*v1; sa2 = wgt*v2; }
        else         { sa0 = fmaf(wgt, v0, sa0); sa1 = fmaf(wgt, v1, sa1); sa2 = fmaf(wgt, v2, sa2); }
        if (st == 3) { z0 += sa0; z1 += sa1; z2 += sa2; }
    }

    // ---------------- mask, grid-sample, store (group 0 only) ----------------
    if (g == 0) {
        const bool m = (t0 > 0.0f);
        const float q0 = m ? z0 : x0v;
        const float q1 = m ? z1 : x1v;
        const float q2 = m ? z2 : x2v;
        const float dfin = m ? dacc : 0.0f;

        const float px = ((q0 * 0.2f + 1.0f) * 100.0f - 1.0f) * 0.5f;
        const float py = ((q1 * 0.2f + 1.0f) * 100.0f - 1.0f) * 0.5f;
        const float pz = ((q2 * 0.2f + 1.0f) * 100.0f - 1.0f) * 0.5f;
        const float fx = floorf(px), fy = floorf(py), fz = floorf(pz);
        const int ix0 = (int)fx, iy0 = (int)fy, iz0 = (int)fz;
        const float wx1 = px - fx, wy1 = py - fy, wz1 = pz - fz;

        float gs = 0.0f;
        #pragma unroll
        for (int c = 0; c < 8; ++c) {
            const int dxc = c & 1, dyc = (c >> 1) & 1, dzc = (c >> 2) & 1;
            const int ix = ix0 + dxc, iy = iy0 + dyc, iz = iz0 + dzc;
            const float w = (dxc ? wx1 : 1.0f - wx1)
                          * (dyc ? wy1 : 1.0f - wy1)
                          * (dzc ? wz1 : 1.0f - wz1);
            if (ix >= 0 && ix < 100 && iy >= 0 && iy < 100 && iz >= 0 && iz < 100)
                gs += vol[(iz * 100 + iy) * 100 + ix] * w;
        }
        out[idx] = gs - dfin;
    }
}

extern "C" void kernel_launch(void* const* d_in, const int* in_sizes, int n_in,
                              void* d_out, int out_size, void* d_ws, size_t ws_size,
                              hipStream_t stream) {
    const float* x    = (const float*)d_in[0];
    const float* t    = (const float*)d_in[1];
    const float* W1   = (const float*)d_in[2];
    const float* b1   = (const float*)d_in[3];
    const float* W2   = (const float*)d_in[4];
    const float* b2   = (const float*)d_in[5];
    const float* W3   = (const float*)d_in[6];
    const float* b3   = (const float*)d_in[7];
    const float* vol  = (const float*)d_in[8];
    float* out = (float*)d_out;

    dim3 grid(NSAMP / 64), block(256);   // 4 waves/block, 16 samples/wave
    cnf_logp_kernel<<<grid, block, 0, stream>>>(x, t, W1, b1, W2, b2, W3, b3, vol, out);
}

// Round 11
// 108.257 us; speedup vs baseline: 1.2619x; 1.1434x over previous
//
#include <hip/hip_runtime.h>
#include <math.h>

#define NSAMP 131072

typedef _Float16 half8v __attribute__((ext_vector_type(8)));
typedef __fp16   fp16x2 __attribute__((ext_vector_type(2)));
typedef __fp16   fp16x4 __attribute__((ext_vector_type(4)));
typedef __fp16   fp16x8 __attribute__((ext_vector_type(8)));
typedef float    f32x4  __attribute__((ext_vector_type(4)));
typedef float    f32x8  __attribute__((ext_vector_type(8)));

__device__ __forceinline__ float fast_tanh(float x) {
    // valid for all x: exp2 saturates to 0/inf, rcp gives exact +-1 limits
    float e = __builtin_amdgcn_exp2f(x * 2.885390081777927f); // exp(2x)
    return fmaf(-2.0f, __builtin_amdgcn_rcpf(e + 1.0f), 1.0f);
}

__device__ __forceinline__ half8v pack8rtz(f32x8 v) {
    fp16x2 p0 = __builtin_amdgcn_cvt_pkrtz(v[0], v[1]);
    fp16x2 p1 = __builtin_amdgcn_cvt_pkrtz(v[2], v[3]);
    fp16x2 p2 = __builtin_amdgcn_cvt_pkrtz(v[4], v[5]);
    fp16x2 p3 = __builtin_amdgcn_cvt_pkrtz(v[6], v[7]);
    fp16x4 q0 = __builtin_shufflevector(p0, p1, 0, 1, 2, 3);
    fp16x4 q1 = __builtin_shufflevector(p2, p3, 0, 1, 2, 3);
    fp16x8 r  = __builtin_shufflevector(q0, q1, 0, 1, 2, 3, 4, 5, 6, 7);
    return __builtin_bit_cast(half8v, r);
}

__global__ __launch_bounds__(256, 2)
void cnf_logp_kernel(const float* __restrict__ xin, const float* __restrict__ tin,
                     const float* __restrict__ W1, const float* __restrict__ b1,
                     const float* __restrict__ W2, const float* __restrict__ b2,
                     const float* __restrict__ W3, const float* __restrict__ b3,
                     const float* __restrict__ vol, float* __restrict__ out)
{
    const int tid  = threadIdx.x;
    const int lane = tid & 63;
    const int col  = lane & 15;   // sample slot (B/C column); A-row for weight frags
    const int g    = lane >> 4;   // lane group

    // slot k-map shared by ALL frags (hw-map mismatches cancel):
    //   k(e,g) = 4g + (e&3) + 16*(e>>2); e>=4 -> slot >= 16

    // ---------------- layer-1 MFMA A-frags (static) ----------------
    half8v A1[4];   // [kq], rows = k within quarter (= col)
    #pragma unroll
    for (int kq = 0; kq < 4; ++kq) {
        half8v a;
        #pragma unroll
        for (int e = 0; e < 8; ++e) a[e] = (_Float16)0.0f;
        const int krow = kq*16 + col;
        #pragma unroll
        for (int e = 0; e < 4; ++e) {
            const float w = W1[e*64 + krow];
            const _Float16 whi = (_Float16)w;
            const _Float16 wlo = (_Float16)(w - (float)whi);
            _Float16 v = (_Float16)0.0f;
            if (g == 0 || g == 2)      v = whi;
            else if (g == 1)           v = wlo;
            else {                     // g == 3: bias slots 12/13
                const float bv = b1[krow];
                const _Float16 bhi = (_Float16)bv;
                if (e == 0)      v = bhi;
                else if (e == 1) v = (_Float16)(bv - (float)bhi);
            }
            a[e] = v;
        }
        A1[kq] = a;
    }

    // ---------------- layer-2 weight A-frags (rows = j) ----------------
    half8v AW2[8];   // [nt*2+kh] : A[j = nt*16+col, k] = W2[k, j]
    half8v AHW[8];   // H[k,j] = W2[k,j] * sum_i W1[i,k] W3[j,i]
    #pragma unroll
    for (int nt = 0; nt < 4; ++nt) {
        const int j = nt*16 + col;
        const float w3j0 = W3[j*3+0], w3j1 = W3[j*3+1], w3j2 = W3[j*3+2];
        #pragma unroll
        for (int kh = 0; kh < 2; ++kh) {
            #pragma unroll
            for (int e = 0; e < 8; ++e) {
                const int k = kh*32 + 4*g + (e & 3) + 16*(e >> 2);
                const float w2v = W2[k*64 + j];
                const float gv  = W1[0*64+k]*w3j0 + W1[1*64+k]*w3j1 + W1[2*64+k]*w3j2;
                AW2[nt*2 + kh][e] = (_Float16)w2v;
                AHW[nt*2 + kh][e] = (_Float16)(w2v * gv);
            }
        }
    }
    // b2 in OUTPUT-j indexing: j_out = nt*16 + 4g + r
    f32x4 b2v[4];
    #pragma unroll
    for (int nt = 0; nt < 4; ++nt) {
        #pragma unroll
        for (int r = 0; r < 4; ++r) b2v[nt][r] = b2[nt*16 + 4*g + r];
    }
    // W3 A-frags for the f-MFMA: rows = channel (col<3), K = j
    half8v A3[2];
    #pragma unroll
    for (int kp = 0; kp < 2; ++kp) {
        #pragma unroll
        for (int e = 0; e < 8; ++e) {
            const int j = kp*32 + 4*g + (e & 3) + 16*(e >> 2);
            A3[kp][e] = (col < 3) ? (_Float16)W3[j*3 + col] : (_Float16)0.0f;
        }
    }
    const float b3c0 = b3[0], b3c1 = b3[1], b3c2 = b3[2];

    // ---------------- per-sample state (sample = col, replicated x4 groups) ----------------
    const int idx = blockIdx.x*64 + (tid >> 6)*16 + col;
    const float x0v = xin[idx*3 + 0], x1v = xin[idx*3 + 1], x2v = xin[idx*3 + 2];
    const float t0  = tin[idx];

    float z0 = x0v, z1 = x1v, z2 = x2v;
    float dacc = 0.0f;
    const float hstep = 0.25f;
    float kz0 = 0.f, kz1 = 0.f, kz2 = 0.f;
    float sa0 = 0.f, sa1 = 0.f, sa2 = 0.f;

    const bool g2f = (g == 2), g3f = (g == 3);

    #pragma unroll 1
    for (int it = 0; it < 16; ++it) {
        const int st   = it & 3;
        const int step = it >> 2;
        const float alpha = (st == 0) ? 0.0f : ((st == 3) ? hstep : 0.5f * hstep);
        const float wgt   = (st == 1 || st == 2) ? (hstep * (1.0f/3.0f)) : (hstep * (1.0f/6.0f));
        const float s     = (float)step * hstep + alpha;
        const float zi0 = fmaf(alpha, kz0, z0);
        const float zi1 = fmaf(alpha, kz1, z1);
        const float zi2 = fmaf(alpha, kz2, z2);
        const float tt  = t0 * (1.0f - s);

        // ---- layer 1 via MFMA: B-frag carries [zhi | zhi | zlo | 1] by group ----
        const _Float16 z0h = (_Float16)zi0, z1h = (_Float16)zi1,
                       z2h = (_Float16)zi2, tth = (_Float16)tt;
        const _Float16 z0l = (_Float16)(zi0 - (float)z0h);
        const _Float16 z1l = (_Float16)(zi1 - (float)z1h);
        const _Float16 z2l = (_Float16)(zi2 - (float)z2h);
        const _Float16 ttl = (_Float16)(tt  - (float)tth);
        half8v B1;
        #pragma unroll
        for (int e = 0; e < 8; ++e) B1[e] = (_Float16)0.0f;
        B1[0] = g3f ? (_Float16)1.0f : (g2f ? z0l : z0h);
        B1[1] = g3f ? (_Float16)1.0f : (g2f ? z1l : z1h);
        B1[2] = g3f ? (_Float16)0.0f : (g2f ? z2l : z2h);
        B1[3] = g3f ? (_Float16)0.0f : (g2f ? ttl : tth);

        f32x8 hv[2];   // [kh], element (kq&1)*4 + r
        #pragma unroll
        for (int kq = 0; kq < 4; ++kq) {
            f32x4 z4; z4[0]=0.f; z4[1]=0.f; z4[2]=0.f; z4[3]=0.f;
            z4 = __builtin_amdgcn_mfma_f32_16x16x32_f16(A1[kq], B1, z4, 0, 0, 0);
            #pragma unroll
            for (int r = 0; r < 4; ++r)
                hv[kq >> 1][(kq & 1)*4 + r] = fast_tanh(z4[r]);
        }

        // ---- pack h -> layer-2 B-frags ----
        half8v BH[2], BQ[2];
        half8v hone;
        #pragma unroll
        for (int e = 0; e < 8; ++e) hone[e] = (_Float16)1.0f;
        #pragma unroll
        for (int kh = 0; kh < 2; ++kh) {
            BH[kh] = pack8rtz(hv[kh]);
            BQ[kh] = hone - BH[kh]*BH[kh];   // s1 = 1 - h^2 (packed)
        }

        // ---- layer 2 + divergence bilinear (cs folded): D[j, sample] ----
        f32x4 a2[4], d2[4];
        #pragma unroll
        for (int nt = 0; nt < 4; ++nt) {
            f32x4 acc = b2v[nt];
            acc = __builtin_amdgcn_mfma_f32_16x16x32_f16(AW2[nt*2+0], BH[0], acc, 0, 0, 0);
            acc = __builtin_amdgcn_mfma_f32_16x16x32_f16(AW2[nt*2+1], BH[1], acc, 0, 0, 0);
            a2[nt] = acc;
            f32x4 z4; z4[0]=0.f; z4[1]=0.f; z4[2]=0.f; z4[3]=0.f;
            z4  = __builtin_amdgcn_mfma_f32_16x16x32_f16(AHW[nt*2+0], BQ[0], z4, 0, 0, 0);
            z4  = __builtin_amdgcn_mfma_f32_16x16x32_f16(AHW[nt*2+1], BQ[1], z4, 0, 0, 0);
            d2[nt] = z4;
        }

        // ---- epilogue: per-lane j-slice (j = nt*16 + 4g + r), sample = col ----
        f32x8 h2v[2];  // [nt>>1], element (nt&1)*4 + r
        float pdv = 0.0f;
        #pragma unroll
        for (int nt = 0; nt < 4; ++nt) {
            #pragma unroll
            for (int r = 0; r < 4; ++r) {
                const float h2 = fast_tanh(a2[nt][r]);
                h2v[nt >> 1][(nt & 1)*4 + r] = h2;
                const float s2 = fmaf(-h2, h2, 1.0f);
                pdv = fmaf(s2, d2[nt][r], pdv);
            }
        }
        // f = h2 @ W3 via 2nd-level MFMA: tanh(a2) repacks as K=j B-frag
        half8v B2h0 = pack8rtz(h2v[0]);
        half8v B2h1 = pack8rtz(h2v[1]);
        f32x4 fD; fD[0]=0.f; fD[1]=0.f; fD[2]=0.f; fD[3]=0.f;
        fD = __builtin_amdgcn_mfma_f32_16x16x32_f16(A3[0], B2h0, fD, 0, 0, 0);
        fD = __builtin_amdgcn_mfma_f32_16x16x32_f16(A3[1], B2h1, fD, 0, 0, 0);

        // dv: sum over 4 groups; f: rows 0..2 live in group-0 lanes
        pdv += __shfl_xor(pdv, 16);
        pdv += __shfl_xor(pdv, 32);
        const float f0 = __shfl(fD[0], col) + b3c0;
        const float f1 = __shfl(fD[1], col) + b3c1;
        const float f2 = __shfl(fD[2], col) + b3c2;

        // ---- RK4 stage update (sample = col, replicated across groups) ----
        const float v0 = -t0 * f0, v1 = -t0 * f1, v2 = -t0 * f2;
        const float vd =  t0 * pdv;
        kz0 = v0; kz1 = v1; kz2 = v2;
        dacc = fmaf(wgt, vd, dacc);
        if (st == 0) { sa0 = wgt*v0; sa1 = wgt*v1; sa2 = wgt*v2; }
        else         { sa0 = fmaf(wgt, v0, sa0); sa1 = fmaf(wgt, v1, sa1); sa2 = fmaf(wgt, v2, sa2); }
        if (st == 3) { z0 += sa0; z1 += sa1; z2 += sa2; }
    }

    // ---------------- mask, grid-sample, store (group 0 only) ----------------
    if (g == 0) {
        const bool m = (t0 > 0.0f);
        const float q0 = m ? z0 : x0v;
        const float q1 = m ? z1 : x1v;
        const float q2 = m ? z2 : x2v;
        const float dfin = m ? dacc : 0.0f;

        const float px = ((q0 * 0.2f + 1.0f) * 100.0f - 1.0f) * 0.5f;
        const float py = ((q1 * 0.2f + 1.0f) * 100.0f - 1.0f) * 0.5f;
        const float pz = ((q2 * 0.2f + 1.0f) * 100.0f - 1.0f) * 0.5f;
        const float fx = floorf(px), fy = floorf(py), fz = floorf(pz);
        const int ix0 = (int)fx, iy0 = (int)fy, iz0 = (int)fz;
        const float wx1 = px - fx, wy1 = py - fy, wz1 = pz - fz;

        float gs = 0.0f;
        #pragma unroll
        for (int c = 0; c < 8; ++c) {
            const int dxc = c & 1, dyc = (c >> 1) & 1, dzc = (c >> 2) & 1;
            const int ix = ix0 + dxc, iy = iy0 + dyc, iz = iz0 + dzc;
            const float w = (dxc ? wx1 : 1.0f - wx1)
                          * (dyc ? wy1 : 1.0f - wy1)
                          * (dzc ? wz1 : 1.0f - wz1);
            if (ix >= 0 && ix < 100 && iy >= 0 && iy < 100 && iz >= 0 && iz < 100)
                gs += vol[(iz * 100 + iy) * 100 + ix] * w;
        }
        out[idx] = gs - dfin;
    }
}

extern "C" void kernel_launch(void* const* d_in, const int* in_sizes, int n_in,
                              void* d_out, int out_size, void* d_ws, size_t ws_size,
                              hipStream_t stream) {
    const float* x    = (const float*)d_in[0];
    const float* t    = (const float*)d_in[1];
    const float* W1   = (const float*)d_in[2];
    const float* b1   = (const float*)d_in[3];
    const float* W2   = (const float*)d_in[4];
    const float* b2   = (const float*)d_in[5];
    const float* W3   = (const float*)d_in[6];
    const float* b3   = (const float*)d_in[7];
    const float* vol  = (const float*)d_in[8];
    float* out = (float*)d_out;

    dim3 grid(NSAMP / 64), block(256);   // 4 waves/block, 16 samples/wave
    cnf_logp_kernel<<<grid, block, 0, stream>>>(x, t, W1, b1, W2, b2, W3, b3, vol, out);
}

// Round 12
// 90.487 us; speedup vs baseline: 1.5097x; 1.1964x over previous
//
#include <hip/hip_runtime.h>
#include <math.h>

#define NSAMP 131072

typedef _Float16 half8v __attribute__((ext_vector_type(8)));
typedef __fp16   fp16x2 __attribute__((ext_vector_type(2)));
typedef __fp16   fp16x4 __attribute__((ext_vector_type(4)));
typedef __fp16   fp16x8 __attribute__((ext_vector_type(8)));
typedef float    f32x16 __attribute__((ext_vector_type(16)));

__device__ __forceinline__ float fast_tanh(float x) {
    // valid for all x: exp2 saturates to 0/inf, rcp gives exact +-1 limits
    float e = __builtin_amdgcn_exp2f(x * 2.885390081777927f); // exp(2x)
    return fmaf(-2.0f, __builtin_amdgcn_rcpf(e + 1.0f), 1.0f);
}

__device__ __forceinline__ half8v pack8f(float v0, float v1, float v2, float v3,
                                         float v4, float v5, float v6, float v7) {
    fp16x2 p0 = __builtin_amdgcn_cvt_pkrtz(v0, v1);
    fp16x2 p1 = __builtin_amdgcn_cvt_pkrtz(v2, v3);
    fp16x2 p2 = __builtin_amdgcn_cvt_pkrtz(v4, v5);
    fp16x2 p3 = __builtin_amdgcn_cvt_pkrtz(v6, v7);
    fp16x4 q0 = __builtin_shufflevector(p0, p1, 0, 1, 2, 3);
    fp16x4 q1 = __builtin_shufflevector(p2, p3, 0, 1, 2, 3);
    fp16x8 r  = __builtin_shufflevector(q0, q1, 0, 1, 2, 3, 4, 5, 6, 7);
    return __builtin_bit_cast(half8v, r);
}
__device__ __forceinline__ half8v pack8lo(const f32x16 v) {
    return pack8f(v[0], v[1], v[2], v[3], v[4], v[5], v[6], v[7]);
}
__device__ __forceinline__ half8v pack8hi(const f32x16 v) {
    return pack8f(v[8], v[9], v[10], v[11], v[12], v[13], v[14], v[15]);
}

// 32x32x16 f16 MFMA conventions used here:
//  - K-slot map (MY convention, shared by A and B of every MFMA so HW wiring
//    permutations cancel): k = kt*16 + 4*g2 + (e&3) + 8*(e>>2), g2 = lane>>5.
//  - C/D layout (HW-verified m74/m101): col = lane&31,
//    row = (reg&3) + 8*(reg>>2) + 4*g2.
//  - chain identity: value at C rows [g2-half] chunk reg 0..7 / 8..15 feeds
//    B-frag K-tile kt as pack8lo/pack8hi of the rt = kt>>1 C result.

__global__ __launch_bounds__(256, 2)
void cnf_logp_kernel(const float* __restrict__ xin, const float* __restrict__ tin,
                     const float* __restrict__ W1, const float* __restrict__ b1,
                     const float* __restrict__ W2, const float* __restrict__ b2,
                     const float* __restrict__ W3, const float* __restrict__ b3,
                     const float* __restrict__ vol, float* __restrict__ out)
{
    const int tid  = threadIdx.x;
    const int lane = tid & 63;
    const int col  = lane & 31;   // sample slot (B/C column); A-row for weight frags
    const int g2   = lane >> 5;   // K-slot half

    // ---------------- layer-1 A-frags: rows k (2 tiles), K=16 planes ----------------
    // planes by slot>>2: 0=W1hi, 1=W1lo, 2=bias(b1hi,b1lo), 3=zero
    // g2=0 lanes carry slots {0-3, 8-11} -> planes 0,2 ; g2=1 -> {4-7,12-15} -> 1,3
    half8v A1[2];
    #pragma unroll
    for (int rt = 0; rt < 2; ++rt) {
        half8v a;
        const int krow = rt*32 + col;
        #pragma unroll
        for (int e = 0; e < 4; ++e) {
            const float w = W1[e*64 + krow];
            const _Float16 whi = (_Float16)w;
            const _Float16 wlo = (_Float16)(w - (float)whi);
            a[e] = g2 ? wlo : whi;
        }
        const float bv = b1[krow];
        const _Float16 bhi = (_Float16)bv;
        const _Float16 blo = (_Float16)(bv - (float)bhi);
        a[4] = g2 ? (_Float16)0.0f : bhi;
        a[5] = g2 ? (_Float16)0.0f : blo;
        a[6] = (_Float16)0.0f;
        a[7] = (_Float16)0.0f;
        A1[rt] = a;
    }

    // ---------------- layer-2 weight A-frags: rows j (2 tiles), K=k (4 tiles) ----------------
    half8v AW2[8];   // [jt*4+kt] : A[j = jt*32+col, k]
    half8v AHW[8];   // H[k,j] = W2[k,j] * sum_i W1[i,k] W3[j,i]
    #pragma unroll
    for (int jt = 0; jt < 2; ++jt) {
        const int j = jt*32 + col;
        const float w3j0 = W3[j*3+0], w3j1 = W3[j*3+1], w3j2 = W3[j*3+2];
        #pragma unroll
        for (int kt = 0; kt < 4; ++kt) {
            half8v w2q, hq;
            #pragma unroll
            for (int e = 0; e < 8; ++e) {
                const int k = kt*16 + 4*g2 + (e & 3) + 8*(e >> 2);
                const float w2v = W2[k*64 + j];
                const float gv  = W1[0*64+k]*w3j0 + W1[1*64+k]*w3j1 + W1[2*64+k]*w3j2;
                w2q[e] = (_Float16)w2v;
                hq[e]  = (_Float16)(w2v * gv);
            }
            AW2[jt*4 + kt] = w2q;
            AHW[jt*4 + kt] = hq;
        }
    }
    // b2 as C-init, C-row indexed
    f32x16 b2C0, b2C1;
    #pragma unroll
    for (int reg = 0; reg < 16; ++reg) {
        const int jr = (reg & 3) + 8*(reg >> 2) + 4*g2;
        b2C0[reg] = b2[jr];
        b2C1[reg] = b2[32 + jr];
    }
    // W3 A-frags for the f-MFMA: rows = channel (col<3), K = j (4 tiles)
    half8v A3[4];
    #pragma unroll
    for (int kt = 0; kt < 4; ++kt) {
        half8v a;
        #pragma unroll
        for (int e = 0; e < 8; ++e) {
            const int j = kt*16 + 4*g2 + (e & 3) + 8*(e >> 2);
            a[e] = (col < 3) ? (_Float16)W3[j*3 + col] : (_Float16)0.0f;
        }
        A3[kt] = a;
    }
    const float b3c0 = b3[0], b3c1 = b3[1], b3c2 = b3[2];

    f32x16 zc;
    #pragma unroll
    for (int i = 0; i < 16; ++i) zc[i] = 0.0f;

    // ---------------- per-sample state (sample = col, replicated x2 halves) ----------------
    const int idx = blockIdx.x*128 + (tid >> 6)*32 + col;
    const float x0v = xin[idx*3 + 0], x1v = xin[idx*3 + 1], x2v = xin[idx*3 + 2];
    const float t0  = tin[idx];

    float z0 = x0v, z1 = x1v, z2 = x2v;
    float dacc = 0.0f;
    const float hstep = 0.25f;
    float kz0 = 0.f, kz1 = 0.f, kz2 = 0.f;
    float sa0 = 0.f, sa1 = 0.f, sa2 = 0.f;

    #pragma unroll 1
    for (int it = 0; it < 16; ++it) {
        const int st   = it & 3;
        const int step = it >> 2;
        const float alpha = (st == 0) ? 0.0f : ((st == 3) ? hstep : 0.5f * hstep);
        const float wgt   = (st == 1 || st == 2) ? (hstep * (1.0f/3.0f)) : (hstep * (1.0f/6.0f));
        const float s     = (float)step * hstep + alpha;
        const float zi0 = fmaf(alpha, kz0, z0);
        const float zi1 = fmaf(alpha, kz1, z1);
        const float zi2 = fmaf(alpha, kz2, z2);
        const float tt  = t0 * (1.0f - s);

        // ---- layer 1 via MFMA: B carries [zhi | zlo | 1-plane | 0] by g2 ----
        const _Float16 z0h = (_Float16)zi0, z1h = (_Float16)zi1,
                       z2h = (_Float16)zi2, tth = (_Float16)tt;
        const _Float16 z0l = (_Float16)(zi0 - (float)z0h);
        const _Float16 z1l = (_Float16)(zi1 - (float)z1h);
        const _Float16 z2l = (_Float16)(zi2 - (float)z2h);
        const _Float16 ttl = (_Float16)(tt  - (float)tth);
        half8v B1v;
        B1v[0] = g2 ? z0l : z0h;
        B1v[1] = g2 ? z1l : z1h;
        B1v[2] = g2 ? z2l : z2h;
        B1v[3] = g2 ? ttl : tth;
        B1v[4] = g2 ? (_Float16)0.0f : (_Float16)1.0f;
        B1v[5] = g2 ? (_Float16)0.0f : (_Float16)1.0f;
        B1v[6] = (_Float16)0.0f;
        B1v[7] = (_Float16)0.0f;

        f32x16 hC0 = __builtin_amdgcn_mfma_f32_32x32x16_f16(A1[0], B1v, zc, 0, 0, 0);
        f32x16 hC1 = __builtin_amdgcn_mfma_f32_32x32x16_f16(A1[1], B1v, zc, 0, 0, 0);
        f32x16 hv0, hv1;
        #pragma unroll
        for (int r = 0; r < 16; ++r) { hv0[r] = fast_tanh(hC0[r]); }
        #pragma unroll
        for (int r = 0; r < 16; ++r) { hv1[r] = fast_tanh(hC1[r]); }

        // ---- pack h -> layer-2 B-frags (chunk-contiguous identity) ----
        half8v BH[4], BQ[4];
        BH[0] = pack8lo(hv0); BH[1] = pack8hi(hv0);
        BH[2] = pack8lo(hv1); BH[3] = pack8hi(hv1);
        half8v hone;
        #pragma unroll
        for (int e = 0; e < 8; ++e) hone[e] = (_Float16)1.0f;
        #pragma unroll
        for (int kt = 0; kt < 4; ++kt) BQ[kt] = hone - BH[kt]*BH[kt];

        // ---- layer 2 + divergence bilinear, jt-serialized; f-frag repack ----
        half8v B2h[4];
        float pdv = 0.0f;
        #pragma unroll
        for (int jt = 0; jt < 2; ++jt) {
            f32x16 a2C = jt ? b2C1 : b2C0;
            a2C = __builtin_amdgcn_mfma_f32_32x32x16_f16(AW2[jt*4+0], BH[0], a2C, 0, 0, 0);
            a2C = __builtin_amdgcn_mfma_f32_32x32x16_f16(AW2[jt*4+1], BH[1], a2C, 0, 0, 0);
            a2C = __builtin_amdgcn_mfma_f32_32x32x16_f16(AW2[jt*4+2], BH[2], a2C, 0, 0, 0);
            a2C = __builtin_amdgcn_mfma_f32_32x32x16_f16(AW2[jt*4+3], BH[3], a2C, 0, 0, 0);
            f32x16 d2C = __builtin_amdgcn_mfma_f32_32x32x16_f16(AHW[jt*4+0], BQ[0], zc, 0, 0, 0);
            d2C = __builtin_amdgcn_mfma_f32_32x32x16_f16(AHW[jt*4+1], BQ[1], d2C, 0, 0, 0);
            d2C = __builtin_amdgcn_mfma_f32_32x32x16_f16(AHW[jt*4+2], BQ[2], d2C, 0, 0, 0);
            d2C = __builtin_amdgcn_mfma_f32_32x32x16_f16(AHW[jt*4+3], BQ[3], d2C, 0, 0, 0);
            f32x16 h2v_;
            #pragma unroll
            for (int r = 0; r < 16; ++r) {
                const float h2 = fast_tanh(a2C[r]);
                h2v_[r] = h2;
                const float s2 = fmaf(-h2, h2, 1.0f);
                pdv = fmaf(s2, d2C[r], pdv);
            }
            B2h[jt*2 + 0] = pack8lo(h2v_);
            B2h[jt*2 + 1] = pack8hi(h2v_);
        }

        // ---- f = h2 @ W3 via MFMA ----
        f32x16 fDC = __builtin_amdgcn_mfma_f32_32x32x16_f16(A3[0], B2h[0], zc, 0, 0, 0);
        fDC = __builtin_amdgcn_mfma_f32_32x32x16_f16(A3[1], B2h[1], fDC, 0, 0, 0);
        fDC = __builtin_amdgcn_mfma_f32_32x32x16_f16(A3[2], B2h[2], fDC, 0, 0, 0);
        fDC = __builtin_amdgcn_mfma_f32_32x32x16_f16(A3[3], B2h[3], fDC, 0, 0, 0);

        // dv: only the g2 split needs crossing; f ch lives at lane=col (g2=0), reg=ch
        pdv += __shfl_xor(pdv, 32);
        const float f0 = __shfl(fDC[0], col) + b3c0;
        const float f1 = __shfl(fDC[1], col) + b3c1;
        const float f2 = __shfl(fDC[2], col) + b3c2;

        // ---- RK4 stage update (sample = col, replicated across halves) ----
        const float v0 = -t0 * f0, v1 = -t0 * f1, v2 = -t0 * f2;
        const float vd =  t0 * pdv;
        kz0 = v0; kz1 = v1; kz2 = v2;
        dacc = fmaf(wgt, vd, dacc);
        if (st == 0) { sa0 = wgt*v0; sa1 = wgt*v1; sa2 = wgt*v2; }
        else         { sa0 = fmaf(wgt, v0, sa0); sa1 = fmaf(wgt, v1, sa1); sa2 = fmaf(wgt, v2, sa2); }
        if (st == 3) { z0 += sa0; z1 += sa1; z2 += sa2; }
    }

    // ---------------- mask, grid-sample, store (half 0 only) ----------------
    if (g2 == 0) {
        const bool m = (t0 > 0.0f);
        const float q0 = m ? z0 : x0v;
        const float q1 = m ? z1 : x1v;
        const float q2 = m ? z2 : x2v;
        const float dfin = m ? dacc : 0.0f;

        const float px = ((q0 * 0.2f + 1.0f) * 100.0f - 1.0f) * 0.5f;
        const float py = ((q1 * 0.2f + 1.0f) * 100.0f - 1.0f) * 0.5f;
        const float pz = ((q2 * 0.2f + 1.0f) * 100.0f - 1.0f) * 0.5f;
        const float fx = floorf(px), fy = floorf(py), fz = floorf(pz);
        const int ix0 = (int)fx, iy0 = (int)fy, iz0 = (int)fz;
        const float wx1 = px - fx, wy1 = py - fy, wz1 = pz - fz;

        float gs = 0.0f;
        #pragma unroll
        for (int c = 0; c < 8; ++c) {
            const int dxc = c & 1, dyc = (c >> 1) & 1, dzc = (c >> 2) & 1;
            const int ix = ix0 + dxc, iy = iy0 + dyc, iz = iz0 + dzc;
            const float w = (dxc ? wx1 : 1.0f - wx1)
                          * (dyc ? wy1 : 1.0f - wy1)
                          * (dzc ? wz1 : 1.0f - wz1);
            if (ix >= 0 && ix < 100 && iy >= 0 && iy < 100 && iz >= 0 && iz < 100)
                gs += vol[(iz * 100 + iy) * 100 + ix] * w;
        }
        out[idx] = gs - dfin;
    }
}

extern "C" void kernel_launch(void* const* d_in, const int* in_sizes, int n_in,
                              void* d_out, int out_size, void* d_ws, size_t ws_size,
                              hipStream_t stream) {
    const float* x    = (const float*)d_in[0];
    const float* t    = (const float*)d_in[1];
    const float* W1   = (const float*)d_in[2];
    const float* b1   = (const float*)d_in[3];
    const float* W2   = (const float*)d_in[4];
    const float* b2   = (const float*)d_in[5];
    const float* W3   = (const float*)d_in[6];
    const float* b3   = (const float*)d_in[7];
    const float* vol  = (const float*)d_in[8];
    float* out = (float*)d_out;

    dim3 grid(NSAMP / 128), block(256);   // 4 waves/block, 32 samples/wave
    cnf_logp_kernel<<<grid, block, 0, stream>>>(x, t, W1, b1, W2, b2, W3, b3, vol, out);
}